// Round 3
// baseline (433.448 us; speedup 1.0000x reference)
//
#include <hip/hip_runtime.h>
#include <math.h>

namespace {
constexpr int NBINS = 8;
constexpr int HW4 = (512 * 512) / 4;   // float4s per (b,c) plane
constexpr int PLANES = 16 * 3;         // B*C
// ln((double)1.01f), 1.01f == 1.0099999904632568359375; accurate to ~1e-17
constexpr double LN_BASE = 0.00995032141084807;
// log1p(2^-24): powf(1.01f,z) rounds above 1.0f iff true value > 1+2^-24
constexpr double LOG1P_EPS = 5.960464299903379e-8;
// log2(1.01f) — kept values only need ~2e-2 accuracy (bf16 compare)
constexpr float LOG2_BASE = 0.014355293f;

typedef float v4f __attribute__((ext_vector_type(4)));
}  // namespace

__global__ __launch_bounds__(256) void hist_kernel(
    const v4f* __restrict__ in, const float* __restrict__ centers,
    const float* __restrict__ wptr, float* __restrict__ out) {
  const int plane = blockIdx.y;                    // b*C + c
  const int i4 = blockIdx.x * 256 + threadIdx.x;   // float4 index in plane
  const float w = wptr[0];

  // Exact fp32 decision threshold: keep iff z > T (real), T = LOG1P_EPS/LN_BASE.
  // For float z this is z > Tf with Tf = largest float < T.
  const double T = LOG1P_EPS / LN_BASE;
  float Tf = (float)T;
  if ((double)Tf >= T) Tf = __builtin_nextafterf(Tf, 0.0f);

  float c[NBINS];
#pragma unroll
  for (int k = 0; k < NBINS; ++k) c[k] = centers[k];

  const v4f x = __builtin_nontemporal_load(in + (size_t)plane * HW4 + i4);

  v4f vv[NBINS];
  float s[NBINS];
#pragma unroll
  for (int k = 0; k < NBINS; ++k) {
    v4f v;
    {
      float z = w - fabsf(x.x - c[k]);
      v.x = (z > Tf) ? exp2f(z * LOG2_BASE) : 0.0f;
      z = w - fabsf(x.y - c[k]);
      v.y = (z > Tf) ? exp2f(z * LOG2_BASE) : 0.0f;
      z = w - fabsf(x.z - c[k]);
      v.z = (z > Tf) ? exp2f(z * LOG2_BASE) : 0.0f;
      z = w - fabsf(x.w - c[k]);
      v.w = (z > Tf) ? exp2f(z * LOG2_BASE) : 0.0f;
    }
    vv[k] = v;
    s[k] = (v.x + v.y) + (v.z + v.w);
  }

  // ---- bin-folding butterfly reduction: 10 shuffles (was 48) ----
  const int lane = threadIdx.x & 63;
  const int h1 = lane & 1;
  float t[4];
#pragma unroll
  for (int k = 0; k < 4; ++k) {
    float keep = h1 ? s[k + 4] : s[k];
    float send = h1 ? s[k] : s[k + 4];
    t[k] = keep + __shfl_xor(send, 1, 64);
  }
  const int h2 = (lane >> 1) & 1;
  float u[2];
#pragma unroll
  for (int k = 0; k < 2; ++k) {
    float keep = h2 ? t[k + 2] : t[k];
    float send = h2 ? t[k] : t[k + 2];
    u[k] = keep + __shfl_xor(send, 2, 64);
  }
  const int h3 = (lane >> 2) & 1;
  {
    float keep = h3 ? u[1] : u[0];
    float send = h3 ? u[0] : u[1];
    float v0 = keep + __shfl_xor(send, 4, 64);
    v0 += __shfl_xor(v0, 8, 64);
    v0 += __shfl_xor(v0, 16, 64);
    v0 += __shfl_xor(v0, 32, 64);
    // lane<8 holds full wave sum of bin (4*h1 + 2*h2 + h3)
    __shared__ float part[4][NBINS];
    const int wv = threadIdx.x >> 6;
    if (lane < NBINS) part[wv][4 * h1 + 2 * h2 + h3] = v0;
    __syncthreads();
    if (threadIdx.x < NBINS) {
      float s8 = (part[0][threadIdx.x] + part[1][threadIdx.x]) +
                 (part[2][threadIdx.x] + part[3][threadIdx.x]);
      atomicAdd(out + plane * NBINS + threadIdx.x, s8 * (1.0f / 262144.0f));
    }
  }

  // ---- streaming stores LAST: no barrier after, kernel ends fire-and-forget ----
  v4f* const out2 = reinterpret_cast<v4f*>(out + PLANES * NBINS) +
                    (size_t)plane * NBINS * HW4 + i4;
#pragma unroll
  for (int k = 0; k < NBINS; ++k)
    __builtin_nontemporal_store(vv[k], out2 + (size_t)k * HW4);
}

extern "C" void kernel_launch(void* const* d_in, const int* in_sizes, int n_in,
                              void* d_out, int out_size, void* d_ws, size_t ws_size,
                              hipStream_t stream) {
  const v4f* in = (const v4f*)d_in[0];
  const float* centers = (const float*)d_in[1];
  const float* width = (const float*)d_in[2];
  float* out = (float*)d_out;
  // one_d region (first 384 floats) accumulates via atomics — zero it each call
  (void)hipMemsetAsync(d_out, 0, PLANES * NBINS * sizeof(float), stream);
  hist_kernel<<<dim3(256, PLANES), 256, 0, stream>>>(in, centers, width, out);
}